// Round 1
// baseline (120.906 us; speedup 1.0000x reference)
//
#include <hip/hip_runtime.h>
#include <hip/hip_bf16.h>

#define NN 4096

typedef unsigned short u16;
typedef __attribute__((ext_vector_type(8))) short bf16x8;
typedef __attribute__((ext_vector_type(4))) float f32x4;

// fp32 -> bf16 round-to-nearest-even (inputs are finite N(0,1); no NaN/Inf care)
static __device__ __forceinline__ u16 f2bf(float x) {
  unsigned u = __float_as_uint(x);
  u += 0x7fff + ((u >> 16) & 1);
  return (u16)(u >> 16);
}

// async global->LDS, 16B per lane; LDS dest = wave-uniform base + lane*16
static __device__ __forceinline__ void gload_lds16(const void* g, void* l) {
  __builtin_amdgcn_global_load_lds(
      (const __attribute__((address_space(1))) void*)g,
      (__attribute__((address_space(3))) void*)l, 16, 0, 0);
}

// ---------------------------------------------------------------------------
// Pass 1a: Ab[i][k] = (k<=i) ? bf16(A[i][k]) : 0   (row-major, tril-masked)
// ---------------------------------------------------------------------------
__global__ void convertA(const float* __restrict__ A, u16* __restrict__ Ab) {
  const long total = (long)NN * NN / 4;  // float4 count
  for (long idx = (long)blockIdx.x * blockDim.x + threadIdx.x; idx < total;
       idx += (long)gridDim.x * blockDim.x) {
    const int i = (int)(idx >> 10);           // 1024 float4 per row
    const int k4 = (int)(idx & 1023) << 2;
    float4 v = ((const float4*)A)[idx];
    ushort4 o;
    o.x = (k4 + 0 <= i) ? f2bf(v.x) : (u16)0;
    o.y = (k4 + 1 <= i) ? f2bf(v.y) : (u16)0;
    o.z = (k4 + 2 <= i) ? f2bf(v.z) : (u16)0;
    o.w = (k4 + 3 <= i) ? f2bf(v.w) : (u16)0;
    ((ushort4*)Ab)[idx] = o;
  }
}

// ---------------------------------------------------------------------------
// Pass 1b: Bt[n][k] = (n<=k) ? bf16(B[k][n]) : 0   (transposed + tril-masked)
// 64x64 tiles via LDS so both global read and write stay coalesced.
// ---------------------------------------------------------------------------
__global__ void convertB(const float* __restrict__ B, u16* __restrict__ Bt) {
  __shared__ float t[64][65];
  const int n0 = blockIdx.x * 64;  // source cols -> dest rows
  const int k0 = blockIdx.y * 64;  // source rows -> dest cols
  const int tid = threadIdx.x;

  if (n0 > k0 + 63) {  // tile entirely above diagonal of B -> all zeros
    const int n = tid >> 3;
    const int kc = (tid & 7) * 8;
    const uint4 z = {0u, 0u, 0u, 0u};
#pragma unroll
    for (int p = 0; p < 2; ++p)
      *(uint4*)&Bt[(long)(n0 + n + p * 32) * NN + k0 + kc] = z;
    return;
  }

#pragma unroll
  for (int p = 0; p < 4; ++p) {
    const int r = (tid >> 4) + p * 16;      // k offset in tile
    const int c = (tid & 15) * 4;           // n offset in tile
    float4 v = *(const float4*)&B[(long)(k0 + r) * NN + n0 + c];
    const int kg = k0 + r;
    t[r][c + 0] = (n0 + c + 0 <= kg) ? v.x : 0.f;
    t[r][c + 1] = (n0 + c + 1 <= kg) ? v.y : 0.f;
    t[r][c + 2] = (n0 + c + 2 <= kg) ? v.z : 0.f;
    t[r][c + 3] = (n0 + c + 3 <= kg) ? v.w : 0.f;
  }
  __syncthreads();

#pragma unroll
  for (int p = 0; p < 2; ++p) {
    const int n = (tid >> 3) + p * 32;
    const int kc = (tid & 7) * 8;
    union { u16 h[8]; uint4 v; } pk;
#pragma unroll
    for (int j = 0; j < 8; ++j) pk.h[j] = f2bf(t[kc + j][n]);
    *(uint4*)&Bt[(long)(n0 + n) * NN + k0 + kc] = pk.v;
  }
}

// ---------------------------------------------------------------------------
// Pass 2a: zero the strict-upper 128x128 blocks of C
// ---------------------------------------------------------------------------
__global__ void zero_upper(float* __restrict__ C) {
  const int bi = blockIdx.y, bj = blockIdx.x;
  if (bj <= bi) return;
  const int tid = threadIdx.x;
  const float4 z = {0.f, 0.f, 0.f, 0.f};
#pragma unroll
  for (int p = 0; p < 16; ++p) {
    const int r = (tid >> 5) + p * 8;
    ((float4*)&C[(long)(bi * 128 + r) * NN + bj * 128])[tid & 31] = z;
  }
}

// ---------------------------------------------------------------------------
// Pass 2b: lower-triangular blocked bf16 MFMA GEMM (m97 structure).
// 128x128 tile, BK=64, 4 waves (2x2 of 64x64), global_load_lds width 16.
// Inputs are pre-masked, so K in [bj*128, (bi+1)*128) needs no masking.
// ---------------------------------------------------------------------------
__global__ __launch_bounds__(256) void gemm_tril(const u16* __restrict__ Ab,
                                                 const u16* __restrict__ Bt,
                                                 float* __restrict__ C) {
  __shared__ u16 As[128 * 64];
  __shared__ u16 Bs[128 * 64];

  // Block order: bi descending (longest K first) for load balance.
  // Row s (s=0 -> bi=31) has 32-s blocks; cum(s) = s*(65-s)/2.
  const int lb = blockIdx.x;
  int s = 0;
  while ((s + 1) * (65 - (s + 1)) / 2 <= lb) ++s;
  const int bi = 31 - s;
  const int bj = lb - s * (65 - s) / 2;

  const int tid = threadIdx.x;
  const int lane = tid & 63;
  const int wid = tid >> 6;
  const int wm = wid >> 1;   // wave row (0..1)
  const int wn = wid & 1;    // wave col (0..1)

  const int sm = lane >> 3;        // staging: row within 8-row chunk
  const int sk = (lane & 7) * 8;   // staging: k offset (8 bf16 = 16B)

  f32x4 acc[4][4];
#pragma unroll
  for (int i = 0; i < 4; ++i)
#pragma unroll
    for (int j = 0; j < 4; ++j) acc[i][j] = (f32x4){0.f, 0.f, 0.f, 0.f};

  const int nk = 2 * (bi - bj + 1);
  const int rA = bi * 128;
  const int rB = bj * 128;

  for (int kt = 0; kt < nk; ++kt) {
    const int k0 = bj * 128 + kt * 64;
    // ---- stage A (rows of tril(A)) and Bt (rows = cols of tril(B)) ----
#pragma unroll
    for (int c = 0; c < 4; ++c) {
      const int chunk = wid * 4 + c;       // 16 chunks of 8 rows x 64 bf16
      const int m = chunk * 8 + sm;
      gload_lds16(Ab + ((long)(rA + m) * NN + k0 + sk), &As[chunk * 512]);
      gload_lds16(Bt + ((long)(rB + m) * NN + k0 + sk), &Bs[chunk * 512]);
    }
    __syncthreads();  // compiler emits vmcnt(0) drain before s_barrier

    bf16x8 a[2][4], b[2][4];
#pragma unroll
    for (int kk = 0; kk < 2; ++kk)
#pragma unroll
      for (int q = 0; q < 4; ++q) {
        a[kk][q] = *(const bf16x8*)&As[(wm * 64 + q * 16 + (lane & 15)) * 64 +
                                       kk * 32 + (lane >> 4) * 8];
        b[kk][q] = *(const bf16x8*)&Bs[(wn * 64 + q * 16 + (lane & 15)) * 64 +
                                       kk * 32 + (lane >> 4) * 8];
      }
#pragma unroll
    for (int kk = 0; kk < 2; ++kk)
#pragma unroll
      for (int m4 = 0; m4 < 4; ++m4)
#pragma unroll
        for (int n4 = 0; n4 < 4; ++n4)
          acc[m4][n4] = __builtin_amdgcn_mfma_f32_16x16x32_bf16(
              a[kk][m4], b[kk][n4], acc[m4][n4], 0, 0, 0);
    __syncthreads();  // LDS free for next K-step
  }

  // ---- epilogue: C/D layout col=lane&15, row=(lane>>4)*4+r ----
  const int crow = rA + wm * 64 + (lane >> 4) * 4;
  const int ccol = rB + wn * 64 + (lane & 15);
  const bool diag = (bi == bj);
#pragma unroll
  for (int m4 = 0; m4 < 4; ++m4)
#pragma unroll
    for (int n4 = 0; n4 < 4; ++n4)
#pragma unroll
      for (int r = 0; r < 4; ++r) {
        const int gi = crow + m4 * 16 + r;
        const int gj = ccol + n4 * 16;
        float v = acc[m4][n4][r];
        if (diag && gj > gi) v = 0.f;
        C[(long)gi * NN + gj] = v;
      }
}

// ---------------------------------------------------------------------------
// Fallback (only if ws too small): naive fp32, correct but slow.
// ---------------------------------------------------------------------------
__global__ void naive_tril(const float* __restrict__ A,
                           const float* __restrict__ B, float* __restrict__ C) {
  const int j = blockIdx.x * 256 + threadIdx.x;
  const int i = blockIdx.y;
  float s = 0.f;
  for (int k = j; k <= i; ++k) s += A[(long)i * NN + k] * B[(long)k * NN + j];
  C[(long)i * NN + j] = s;  // j>i: zero-trip loop -> 0
}

extern "C" void kernel_launch(void* const* d_in, const int* in_sizes, int n_in,
                              void* d_out, int out_size, void* d_ws,
                              size_t ws_size, hipStream_t stream) {
  const float* A = (const float*)d_in[0];
  const float* B = (const float*)d_in[1];
  float* C = (float*)d_out;

  const size_t need = (size_t)2 * NN * NN * sizeof(u16);  // 64 MB
  if (ws_size >= need) {
    u16* Ab = (u16*)d_ws;
    u16* Bt = Ab + (long)NN * NN;
    convertA<<<2048, 256, 0, stream>>>(A, Ab);
    convertB<<<dim3(64, 64), 256, 0, stream>>>(B, Bt);
    zero_upper<<<dim3(32, 32), 256, 0, stream>>>(C);
    gemm_tril<<<528, 256, 0, stream>>>(Ab, Bt, C);
  } else {
    naive_tril<<<dim3(16, NN), 256, 0, stream>>>(A, B, C);
  }
}